// Round 15
// baseline (164.802 us; speedup 1.0000x reference)
//
#include <hip/hip_runtime.h>

// WinGNN: conv-encode (r13/r14-proven fp16 MFMA conv) -> radius-KNN ->
// 4-layer GNN: agg precompute + barrier-free split-K GEMM (1024 blocks).
//
// Workspace layout (bytes):
//   wfrag @ 0        : 12288 fp16 conv-weight fragments, 24 granules (32768 B slot)
//   enc   @ 32768    : 2048x64 f32 (524288)  [zeroed in setup; conv atomicAdds]
//   h16a  @ 557056   : 2048x512 fp16 (2 MB)
//   h16b  @ 2654208  : 2048x512 fp16 (2 MB)
//   agg16 @ 4751360  : 2048x512 fp16 (2 MB)
//   wT16  @ 6848512  : 8x512x512 fp16 (4 MB)
//   nbr   @ 11042816 : 2048x5 int (40960 slot)
//   den   @ 11083776 : 2048 f32 (stores 1/count)

#define NNODES 2048

typedef __attribute__((ext_vector_type(8))) _Float16 half8;
typedef __attribute__((ext_vector_type(16))) float f32x16;

__device__ inline uint pack2h(float x, float y) {
  ushort a = __builtin_bit_cast(ushort, (_Float16)x);
  ushort b = __builtin_bit_cast(ushort, (_Float16)y);
  return (uint)a | ((uint)b << 16);
}

// ---------- setup: wfrag prep (48 blocks) | wT prep (512) | knn + enc zero (2048) ----------
__global__ __launch_bounds__(256) void setup_kernel(
    const float* __restrict__ conv_w, const float* __restrict__ wsrc_s,
    const float* __restrict__ wsrc_n, const float* __restrict__ pos,
    ushort* __restrict__ wfrag, ushort* __restrict__ wT,
    int* __restrict__ nbr, float* __restrict__ den, float* __restrict__ enc) {
  __shared__ float4 smem4[1040];        // 16640 B, unioned per role
  const int bid = blockIdx.x;
  const int tid = threadIdx.x;

  if (bid < 48) {
    // conv_w [64][3][7][7] -> B-fragments: (((ct*12+kb)*64+lane)*8+j), 12288 total
    int i = bid * 256 + tid;
    int j = i & 7;
    int l = (i >> 3) & 63;
    int q = i >> 9;            // ct*12 + kb
    int kb = q % 12, ct = q / 12;
    int g = 2 * kb + (l >> 5);
    int c = 32 * ct + (l & 31);
    float val = 0.f;
    if (g < 21 && j < 7) val = conv_w[c * 147 + g * 7 + j];
    wfrag[i] = __builtin_bit_cast(ushort, (_Float16)val);
    return;
  }

  if (bid < 560) {
    // w_self/w_nbr [k][n] f32 -> wT16 [m][n][k] fp16
    float(*s)[65] = (float(*)[65])smem4;
    int bid2 = bid - 48;
    int m = bid2 >> 6, kt = (bid2 >> 3) & 7, nt = bid2 & 7;
    const float* in = (m < 4) ? (wsrc_s + m * 262144) : (wsrc_n + (m - 4) * 262144);
    ushort* out = wT + m * 262144;
    int k0 = kt << 6, n0 = nt << 6;
#pragma unroll
    for (int rep = 0; rep < 4; ++rep) {
      int row = (rep << 4) + (tid >> 4);
      int c4 = (tid & 15) << 2;
      float4 v = *(const float4*)&in[(k0 + row) * 512 + n0 + c4];
      s[row][c4] = v.x; s[row][c4 + 1] = v.y; s[row][c4 + 2] = v.z; s[row][c4 + 3] = v.w;
    }
    __syncthreads();
#pragma unroll
    for (int rep = 0; rep < 4; ++rep) {
      int n = (rep << 4) + (tid >> 4);
      int k4 = (tid & 15) << 2;
      ushort4 o;
      o.x = __builtin_bit_cast(ushort, (_Float16)s[k4 + 0][n]);
      o.y = __builtin_bit_cast(ushort, (_Float16)s[k4 + 1][n]);
      o.z = __builtin_bit_cast(ushort, (_Float16)s[k4 + 2][n]);
      o.w = __builtin_bit_cast(ushort, (_Float16)s[k4 + 3][n]);
      *(ushort4*)&out[(n0 + n) * 512 + k0 + k4] = o;
    }
    return;
  }

  // radius-KNN for node i; also zero enc rows for conv's atomicAdd
  {
    float* s_d2 = (float*)smem4;
    int* s_idx = (int*)(s_d2 + NNODES);
    int* s_cnt = (int*)(s_idx + NNODES);
    const int i = bid - 560;
    if (tid < 16) {
      float4 z4 = {0.f, 0.f, 0.f, 0.f};
      ((float4*)(enc + i * 64))[tid] = z4;
    }
    if (tid == 0) *s_cnt = 0;
    __syncthreads();
    const float px = pos[2 * i] * 32.f, py = pos[2 * i + 1] * 32.f;
#pragma unroll
    for (int r = 0; r < 8; ++r) {
      int j = tid + (r << 8);
      float2 q = ((const float2*)pos)[j];
      float dx = q.x * 32.f - px, dy = q.y * 32.f - py;
      float d2 = dx * dx + dy * dy;
      if (d2 <= 2.0f && j != i) {
        int slot = atomicAdd(s_cnt, 1);
        s_d2[slot] = d2;
        s_idx[slot] = j;
      }
    }
    __syncthreads();
    if (tid < 64) {
      const int lane = tid;
      const int cnt = *s_cnt;
      int nf = 0;
#pragma unroll
      for (int k = 0; k < 5; ++k) {
        float best = 1e30f;
        int bslot = 0x7fffffff;
        for (int e = lane; e < cnt; e += 64) {
          float d = s_d2[e];
          if (d < best) { best = d; bslot = e; }
        }
#pragma unroll
        for (int off = 1; off < 64; off <<= 1) {
          float od = __shfl_xor(best, off);
          int os = __shfl_xor(bslot, off);
          if (od < best || (od == best && os < bslot)) { best = od; bslot = os; }
        }
        bool got = (best < 1e30f);
        if (lane == 0) nbr[i * 5 + k] = got ? s_idx[bslot] : -1;
        if (got) { s_d2[bslot] = 1e30f; ++nf; }
      }
      if (lane == 0) den[i] = 1.f / (float)(nf > 0 ? nf : 1);
    }
  }
}

// ---------- conv7x7 s2 SAME + bias + relu + avg pool, fp16 MFMA (r14 verbatim) ----------
// LDS: image [3][37][72] fp16 @0 (15984 B) | wfrag @15984 (24576 B) | pool @40560 (1024 B)
__global__ __launch_bounds__(256, 3) void conv_pool_kernel(
    const float* __restrict__ imgs, const ushort* __restrict__ wfrag,
    const float* __restrict__ cb, float* __restrict__ enc) {
  __shared__ int4 s_all[2599];          // 41584 B
  ushort* s_img = (ushort*)s_all;
  const half8* swf8 = (const half8*)((char*)s_all + 15984);
  float* s_pool = (float*)((char*)s_all + 40560);

  const int n = blockIdx.x >> 1;
  const int r0half = blockIdx.x & 1;    // 0: rows 0-15, 1: rows 16-31
  const int wy = 32 * r0half - 2;       // input window start row
  const int tid = threadIdx.x;
  const int lane = tid & 63;
  const int w = tid >> 6;
  const int hi = lane >> 5;
  const int lo = lane & 31;

  // zero image region (999 int4 = 15984 B)
  int4 z = {0, 0, 0, 0};
  for (int i = tid; i < 999; i += 256) s_all[i] = z;
  __syncthreads();

  // stage wfrag -> LDS (1536 int4)
  const int4* wf4 = (const int4*)wfrag;
  int4* swf4 = (int4*)((char*)s_all + 15984);
#pragma unroll
  for (int r = 0; r < 6; ++r) swf4[tid + r * 256] = wf4[tid + r * 256];

  // stage image window fp32 -> fp16 (3 ic x 37 rows x 16 float4)
  const float4* src = (const float4*)(imgs + (size_t)n * 12288);
  for (int i = tid; i < 1776; i += 256) {
    int ic = i / 592;
    int rem = i - ic * 592;
    int li = rem >> 4, xq = rem & 15;
    int iy = wy + li;
    if (iy >= 0 && iy < 64) {
      float4 v = src[(ic * 64 + iy) * 16 + xq];
      int d = (ic * 37 + li) * 72 + (xq << 2) + 2;   // element index, d%4==2
      ((uint*)s_img)[d >> 1] = pack2h(v.x, v.y);
      ((uint*)s_img)[(d >> 1) + 1] = pack2h(v.z, v.w);
    }
  }

  // per-lane A-fragment base offsets (row-local base for this wave baked in)
  int aoff[12];
#pragma unroll
  for (int kb = 0; kb < 12; ++kb) {
    int g = 2 * kb + hi;
    if (g > 20) g = 20;               // padding group: B-frag is zero
    int ic = g / 7, ky = g - ic * 7;
    aoff[kb] = (ic * 37 + ky) * 144 + 4 * lo + w * 1152;
  }
  const float bias0 = cb[lo];
  const float bias1 = cb[32 + lo];
  float pool0 = 0.f, pool1 = 0.f;
  __syncthreads();

  const char* sb = (const char*)s_img;
  union F { half8 v; uint u[4]; };

#define LOADF(F0, F1, B0, B1, KB, TPADD) do {                                 \
    const char* p_ = (const char*)__builtin_assume_aligned(                   \
        sb + aoff[KB] + (TPADD), 4);                                          \
    __builtin_memcpy(&F0.u[0], p_, 8);                                        \
    __builtin_memcpy(&F0.u[2], p_ + 8, 8);                                    \
    __builtin_memcpy(&F1.u[0], p_ + 288, 8);                                  \
    __builtin_memcpy(&F1.u[2], p_ + 296, 8);                                  \
    B0 = swf8[(KB) * 64 + lane];        B1 = swf8[(12 + (KB)) * 64 + lane];   \
  } while (0)

#pragma unroll
  for (int tp = 0; tp < 2; ++tp) {
    const int tpadd = tp * 576;
    f32x16 a0 = {}, a1 = {}, a2 = {}, a3 = {};
    F f0a, f1a, f0b, f1b;
    half8 b0a, b1a, b0b, b1b;
    LOADF(f0a, f1a, b0a, b1a, 0, tpadd);
#pragma unroll
    for (int kb = 0; kb < 12; kb += 2) {
      LOADF(f0b, f1b, b0b, b1b, kb + 1, tpadd);
      a0 = __builtin_amdgcn_mfma_f32_32x32x16_f16(f0a.v, b0a, a0, 0, 0, 0);
      a1 = __builtin_amdgcn_mfma_f32_32x32x16_f16(f0a.v, b1a, a1, 0, 0, 0);
      a2 = __builtin_amdgcn_mfma_f32_32x32x16_f16(f1a.v, b0a, a2, 0, 0, 0);
      a3 = __builtin_amdgcn_mfma_f32_32x32x16_f16(f1a.v, b1a, a3, 0, 0, 0);
      if (kb + 2 < 12) LOADF(f0a, f1a, b0a, b1a, kb + 2, tpadd);
      a0 = __builtin_amdgcn_mfma_f32_32x32x16_f16(f0b.v, b0b, a0, 0, 0, 0);
      a1 = __builtin_amdgcn_mfma_f32_32x32x16_f16(f0b.v, b1b, a1, 0, 0, 0);
      a2 = __builtin_amdgcn_mfma_f32_32x32x16_f16(f1b.v, b0b, a2, 0, 0, 0);
      a3 = __builtin_amdgcn_mfma_f32_32x32x16_f16(f1b.v, b1b, a3, 0, 0, 0);
    }
    float s0 = 0.f, s1 = 0.f;
#pragma unroll
    for (int r = 0; r < 16; ++r) {
      s0 += fmaxf(a0[r] + bias0, 0.f) + fmaxf(a2[r] + bias0, 0.f);
      s1 += fmaxf(a1[r] + bias1, 0.f) + fmaxf(a3[r] + bias1, 0.f);
    }
    pool0 += s0;
    pool1 += s1;
  }
#undef LOADF

  pool0 += __shfl_xor(pool0, 32);
  pool1 += __shfl_xor(pool1, 32);
  if (lane < 32) {
    s_pool[w * 64 + lo] = pool0;
    s_pool[w * 64 + 32 + lo] = pool1;
  }
  __syncthreads();
  if (tid < 64) {
    float s = s_pool[tid] + s_pool[64 + tid] + s_pool[128 + tid] + s_pool[192 + tid];
    atomicAdd(&enc[n * 64 + tid], s * (1.f / 1024.f));   // 2 addends: order-invariant
  }
}

// ---------- proj: relu(enc @ pw + pb) -> h16 [2048][512] fp16 ----------
__global__ __launch_bounds__(256) void proj_kernel(
    const float* __restrict__ enc, const float* __restrict__ pw,
    const float* __restrict__ pb, ushort* __restrict__ h16) {
  int c = ((blockIdx.x & 1) << 8) | threadIdx.x;
  int r0 = (blockIdx.x >> 1) << 3;
  float bias = pb[c];
  float acc[8];
#pragma unroll
  for (int r = 0; r < 8; ++r) acc[r] = bias;
#pragma unroll 4
  for (int k = 0; k < 64; ++k) {
    float w = pw[k * 512 + c];
#pragma unroll
    for (int r = 0; r < 8; ++r) acc[r] = fmaf(enc[(r0 + r) * 64 + k], w, acc[r]);
  }
#pragma unroll
  for (int r = 0; r < 8; ++r)
    h16[(r0 + r) * 512 + c] = __builtin_bit_cast(ushort, (_Float16)fmaxf(acc[r], 0.f));
}

// ---------- agg16[i][:] = mean of valid h16[nbr[i]][:] (fp16 math = r13 COMBINE) ----------
// 512 blocks x 256 thr; thread = (row i = gid>>6 wave-uniform, col-octet = lane)
__global__ __launch_bounds__(256) void agg_kernel(
    const ushort* __restrict__ h16, const int* __restrict__ nbr,
    const float* __restrict__ den, ushort* __restrict__ agg16) {
  const int gid = blockIdx.x * 256 + threadIdx.x;
  const int i = gid >> 6;               // wave-uniform row
  const int oct = gid & 63;             // 8-col group
  union GU { half8 v; uint u[4]; };
  GU t[5];
  half8 den8;
  {
    _Float16 dh = (_Float16)den[i];
#pragma unroll
    for (int e = 0; e < 8; ++e) den8[e] = dh;
  }
#pragma unroll
  for (int k = 0; k < 5; ++k) {
    int j = nbr[i * 5 + k];             // wave-uniform
    uint m = (j >= 0) ? 0xFFFFFFFFu : 0u;
    const half8* p = (const half8*)(h16 + (j >= 0 ? j : 0) * 512 + oct * 8);
    GU g;
    g.v = *p;
#pragma unroll
    for (int j2 = 0; j2 < 4; ++j2) t[k].u[j2] = g.u[j2] & m;
  }
  half8 s = ((t[0].v + t[1].v) + (t[2].v + t[3].v)) + t[4].v;
  s = s * den8;
  *(half8*)&agg16[i * 512 + oct * 8] = s;
}

// ---------- GNN GEMM: out = relu(h@Ws + agg@Wn + b), split-K x4, barrier-free K-loop ----------
// 1024 blocks (64 bm x 16 bn), 32x32 tile, 4 waves = K-slices of 128.
// Per wave: 8 fully-unrolled steps {4x 16B global loads -> 2 MFMA}, 4-deep prefetch.
// One barrier + 16 KB LDS reduce at the end; epilogue split across waves.
__global__ __launch_bounds__(256) void gnn_gemm_kernel(
    const ushort* __restrict__ h16, const ushort* __restrict__ agg16,
    const ushort* __restrict__ Ws, const ushort* __restrict__ Wn,
    const float* __restrict__ bias, ushort* __restrict__ hout,
    float* __restrict__ fout, int final_layer) {
  __shared__ float s_red[4096];         // [kslice][reg][lane] f32 = 16 KB
  const int tid = threadIdx.x;
  const int lane = tid & 63;
  const int hi = lane >> 5, lo = lane & 31;
  const int w = tid >> 6;               // K-slice 0..3
  const int bm = blockIdx.x >> 4, bn = blockIdx.x & 15;
  const int r0 = bm << 5, c0 = bn << 5;

  const ushort* pA = h16   + (r0 + lo) * 512 + (w << 7) + (hi << 3);
  const ushort* pG = agg16 + (r0 + lo) * 512 + (w << 7) + (hi << 3);
  const ushort* pS = Ws    + (c0 + lo) * 512 + (w << 7) + (hi << 3);
  const ushort* pN = Wn    + (c0 + lo) * 512 + (w << 7) + (hi << 3);

  f32x16 accS = {}, accN = {};
  half8 fa[4], fg[4], fs[4], fn[4];
#define LD(D, S) do {                                                         \
    fa[D] = *(const half8*)(pA + 16 * (S));                                   \
    fg[D] = *(const half8*)(pG + 16 * (S));                                   \
    fs[D] = *(const half8*)(pS + 16 * (S));                                   \
    fn[D] = *(const half8*)(pN + 16 * (S));                                   \
  } while (0)
  LD(0, 0); LD(1, 1); LD(2, 2); LD(3, 3);
#pragma unroll
  for (int s = 0; s < 8; ++s) {
    const int d = s & 3;
    accS = __builtin_amdgcn_mfma_f32_32x32x16_f16(fa[d], fs[d], accS, 0, 0, 0);
    accN = __builtin_amdgcn_mfma_f32_32x32x16_f16(fg[d], fn[d], accN, 0, 0, 0);
    if (s + 4 < 8) LD(d, s + 4);
  }
#undef LD

  // cross-wave K reduce
#pragma unroll
  for (int r = 0; r < 16; ++r)
    s_red[(w << 10) + (r << 6) + lane] = accS[r] + accN[r];
  __syncthreads();

  const float b = bias[c0 + lo];
#pragma unroll
  for (int rr = 0; rr < 4; ++rr) {
    const int r = (w << 2) + rr;
    const int base = (r << 6) + lane;
    float v = s_red[base] + s_red[1024 + base] + s_red[2048 + base]
            + s_red[3072 + base] + b;
    v = fmaxf(v, 0.f);
    const int row = r0 + (r & 3) + ((r >> 2) << 3) + (hi << 2);
    const int col = c0 + lo;
    if (final_layer) fout[row * 512 + col] = v;
    else hout[row * 512 + col] = __builtin_bit_cast(ushort, (_Float16)v);
  }
}

extern "C" void kernel_launch(void* const* d_in, const int* in_sizes, int n_in,
                              void* d_out, int out_size, void* d_ws, size_t ws_size,
                              hipStream_t stream) {
  const float* imgs   = (const float*)d_in[0];
  const float* pos    = (const float*)d_in[1];
  const float* conv_w = (const float*)d_in[2];
  const float* conv_b = (const float*)d_in[3];
  const float* proj_w = (const float*)d_in[4];
  const float* proj_b = (const float*)d_in[5];
  const float* w_self = (const float*)d_in[6];
  const float* w_nbr  = (const float*)d_in[7];
  const float* b_gnn  = (const float*)d_in[8];

  char* ws = (char*)d_ws;
  ushort* wfrag = (ushort*)(ws);
  float*  enc   = (float*) (ws + 32768);
  ushort* h16a  = (ushort*)(ws + 557056);
  ushort* h16b  = (ushort*)(ws + 2654208);
  ushort* agg16 = (ushort*)(ws + 4751360);
  ushort* wT16  = (ushort*)(ws + 6848512);
  int*    nbr   = (int*)   (ws + 11042816);
  float*  den   = (float*) (ws + 11083776);

  setup_kernel<<<2608, 256, 0, stream>>>(conv_w, w_self, w_nbr, pos,
                                         wfrag, wT16, nbr, den, enc);
  conv_pool_kernel<<<2 * NNODES, 256, 0, stream>>>(imgs, wfrag, conv_b, enc);
  proj_kernel<<<512, 256, 0, stream>>>(enc, proj_w, proj_b, h16a);

  for (int l = 0; l < 4; ++l) {
    ushort* hin  = (l & 1) ? h16b : h16a;
    ushort* hnew = (l & 1) ? h16a : h16b;
    agg_kernel<<<512, 256, 0, stream>>>(hin, nbr, den, agg16);
    gnn_gemm_kernel<<<1024, 256, 0, stream>>>(
        hin, agg16, wT16 + l * 262144, wT16 + (4 + l) * 262144,
        b_gnn + l * 512, hnew, (float*)d_out, (l == 3) ? 1 : 0);
  }
}

// Round 16
// 149.269 us; speedup vs baseline: 1.1041x; 1.1041x over previous
//
#include <hip/hip_runtime.h>

// WinGNN: conv-encode (r13/r14-proven fp16 MFMA conv) -> radius-KNN ->
// 4-layer GNN (r13 fused-agg staged GEMM, split-K x2 + f32 partial reduce).
//
// Workspace layout (bytes):
//   wfrag @ 0        : 12288 fp16 conv-weight fragments, 24 granules (32768 B slot)
//   enc   @ 32768    : 2048x64 f32 (524288)  [zeroed in setup; conv atomicAdds]
//   h16a  @ 557056   : 2048x512 fp16 (2 MB)
//   h16b  @ 2654208  : 2048x512 fp16 (2 MB)
//   wT16  @ 6848512  : 8x512x512 fp16 (4 MB)
//   nbr   @ 11042816 : 2048x5 int (40960 slot)
//   den   @ 11083776 : 2048 f32 (stores 1/count)
//   part  @ 11534336 : 2x2048x512 f32 (8 MB) split-K partials

#define NNODES 2048

typedef __attribute__((ext_vector_type(8))) _Float16 half8;
typedef __attribute__((ext_vector_type(16))) float f32x16;

__device__ inline uint pack2h(float x, float y) {
  ushort a = __builtin_bit_cast(ushort, (_Float16)x);
  ushort b = __builtin_bit_cast(ushort, (_Float16)y);
  return (uint)a | ((uint)b << 16);
}

// ---------- setup: wfrag prep (48 blocks) | wT prep (512) | knn + enc zero (2048) ----------
__global__ __launch_bounds__(256) void setup_kernel(
    const float* __restrict__ conv_w, const float* __restrict__ wsrc_s,
    const float* __restrict__ wsrc_n, const float* __restrict__ pos,
    ushort* __restrict__ wfrag, ushort* __restrict__ wT,
    int* __restrict__ nbr, float* __restrict__ den, float* __restrict__ enc) {
  __shared__ float4 smem4[1040];        // 16640 B, unioned per role
  const int bid = blockIdx.x;
  const int tid = threadIdx.x;

  if (bid < 48) {
    // conv_w [64][3][7][7] -> B-fragments: (((ct*12+kb)*64+lane)*8+j), 12288 total
    int i = bid * 256 + tid;
    int j = i & 7;
    int l = (i >> 3) & 63;
    int q = i >> 9;            // ct*12 + kb
    int kb = q % 12, ct = q / 12;
    int g = 2 * kb + (l >> 5);
    int c = 32 * ct + (l & 31);
    float val = 0.f;
    if (g < 21 && j < 7) val = conv_w[c * 147 + g * 7 + j];
    wfrag[i] = __builtin_bit_cast(ushort, (_Float16)val);
    return;
  }

  if (bid < 560) {
    // w_self/w_nbr [k][n] f32 -> wT16 [m][n][k] fp16
    float(*s)[65] = (float(*)[65])smem4;
    int bid2 = bid - 48;
    int m = bid2 >> 6, kt = (bid2 >> 3) & 7, nt = bid2 & 7;
    const float* in = (m < 4) ? (wsrc_s + m * 262144) : (wsrc_n + (m - 4) * 262144);
    ushort* out = wT + m * 262144;
    int k0 = kt << 6, n0 = nt << 6;
#pragma unroll
    for (int rep = 0; rep < 4; ++rep) {
      int row = (rep << 4) + (tid >> 4);
      int c4 = (tid & 15) << 2;
      float4 v = *(const float4*)&in[(k0 + row) * 512 + n0 + c4];
      s[row][c4] = v.x; s[row][c4 + 1] = v.y; s[row][c4 + 2] = v.z; s[row][c4 + 3] = v.w;
    }
    __syncthreads();
#pragma unroll
    for (int rep = 0; rep < 4; ++rep) {
      int n = (rep << 4) + (tid >> 4);
      int k4 = (tid & 15) << 2;
      ushort4 o;
      o.x = __builtin_bit_cast(ushort, (_Float16)s[k4 + 0][n]);
      o.y = __builtin_bit_cast(ushort, (_Float16)s[k4 + 1][n]);
      o.z = __builtin_bit_cast(ushort, (_Float16)s[k4 + 2][n]);
      o.w = __builtin_bit_cast(ushort, (_Float16)s[k4 + 3][n]);
      *(ushort4*)&out[(n0 + n) * 512 + k0 + k4] = o;
    }
    return;
  }

  // radius-KNN for node i; also zero enc rows for conv's atomicAdd
  {
    float* s_d2 = (float*)smem4;
    int* s_idx = (int*)(s_d2 + NNODES);
    int* s_cnt = (int*)(s_idx + NNODES);
    const int i = bid - 560;
    if (tid < 16) {
      float4 z4 = {0.f, 0.f, 0.f, 0.f};
      ((float4*)(enc + i * 64))[tid] = z4;
    }
    if (tid == 0) *s_cnt = 0;
    __syncthreads();
    const float px = pos[2 * i] * 32.f, py = pos[2 * i + 1] * 32.f;
#pragma unroll
    for (int r = 0; r < 8; ++r) {
      int j = tid + (r << 8);
      float2 q = ((const float2*)pos)[j];
      float dx = q.x * 32.f - px, dy = q.y * 32.f - py;
      float d2 = dx * dx + dy * dy;
      if (d2 <= 2.0f && j != i) {
        int slot = atomicAdd(s_cnt, 1);
        s_d2[slot] = d2;
        s_idx[slot] = j;
      }
    }
    __syncthreads();
    if (tid < 64) {
      const int lane = tid;
      const int cnt = *s_cnt;
      int nf = 0;
#pragma unroll
      for (int k = 0; k < 5; ++k) {
        float best = 1e30f;
        int bslot = 0x7fffffff;
        for (int e = lane; e < cnt; e += 64) {
          float d = s_d2[e];
          if (d < best) { best = d; bslot = e; }
        }
#pragma unroll
        for (int off = 1; off < 64; off <<= 1) {
          float od = __shfl_xor(best, off);
          int os = __shfl_xor(bslot, off);
          if (od < best || (od == best && os < bslot)) { best = od; bslot = os; }
        }
        bool got = (best < 1e30f);
        if (lane == 0) nbr[i * 5 + k] = got ? s_idx[bslot] : -1;
        if (got) { s_d2[bslot] = 1e30f; ++nf; }
      }
      if (lane == 0) den[i] = 1.f / (float)(nf > 0 ? nf : 1);
    }
  }
}

// ---------- conv7x7 s2 SAME + bias + relu + avg pool, fp16 MFMA (70.0us-proven verbatim) ----------
// LDS: image [3][37][72] fp16 @0 (15984 B) | wfrag @15984 (24576 B) | pool @40560 (1024 B)
__global__ __launch_bounds__(256, 3) void conv_pool_kernel(
    const float* __restrict__ imgs, const ushort* __restrict__ wfrag,
    const float* __restrict__ cb, float* __restrict__ enc) {
  __shared__ int4 s_all[2599];          // 41584 B
  ushort* s_img = (ushort*)s_all;
  const half8* swf8 = (const half8*)((char*)s_all + 15984);
  float* s_pool = (float*)((char*)s_all + 40560);

  const int n = blockIdx.x >> 1;
  const int r0half = blockIdx.x & 1;    // 0: rows 0-15, 1: rows 16-31
  const int wy = 32 * r0half - 2;       // input window start row
  const int tid = threadIdx.x;
  const int lane = tid & 63;
  const int w = tid >> 6;
  const int hi = lane >> 5;
  const int lo = lane & 31;

  // zero image region (999 int4 = 15984 B)
  int4 z = {0, 0, 0, 0};
  for (int i = tid; i < 999; i += 256) s_all[i] = z;
  __syncthreads();

  // stage wfrag -> LDS (1536 int4)
  const int4* wf4 = (const int4*)wfrag;
  int4* swf4 = (int4*)((char*)s_all + 15984);
#pragma unroll
  for (int r = 0; r < 6; ++r) swf4[tid + r * 256] = wf4[tid + r * 256];

  // stage image window fp32 -> fp16 (3 ic x 37 rows x 16 float4)
  const float4* src = (const float4*)(imgs + (size_t)n * 12288);
  for (int i = tid; i < 1776; i += 256) {
    int ic = i / 592;
    int rem = i - ic * 592;
    int li = rem >> 4, xq = rem & 15;
    int iy = wy + li;
    if (iy >= 0 && iy < 64) {
      float4 v = src[(ic * 64 + iy) * 16 + xq];
      int d = (ic * 37 + li) * 72 + (xq << 2) + 2;   // element index, d%4==2
      ((uint*)s_img)[d >> 1] = pack2h(v.x, v.y);
      ((uint*)s_img)[(d >> 1) + 1] = pack2h(v.z, v.w);
    }
  }

  // per-lane A-fragment base offsets (row-local base for this wave baked in)
  int aoff[12];
#pragma unroll
  for (int kb = 0; kb < 12; ++kb) {
    int g = 2 * kb + hi;
    if (g > 20) g = 20;               // padding group: B-frag is zero
    int ic = g / 7, ky = g - ic * 7;
    aoff[kb] = (ic * 37 + ky) * 144 + 4 * lo + w * 1152;
  }
  const float bias0 = cb[lo];
  const float bias1 = cb[32 + lo];
  float pool0 = 0.f, pool1 = 0.f;
  __syncthreads();

  const char* sb = (const char*)s_img;
  union F { half8 v; uint u[4]; };

#define LOADF(F0, F1, B0, B1, KB, TPADD) do {                                 \
    const char* p_ = (const char*)__builtin_assume_aligned(                   \
        sb + aoff[KB] + (TPADD), 4);                                          \
    __builtin_memcpy(&F0.u[0], p_, 8);                                        \
    __builtin_memcpy(&F0.u[2], p_ + 8, 8);                                    \
    __builtin_memcpy(&F1.u[0], p_ + 288, 8);                                  \
    __builtin_memcpy(&F1.u[2], p_ + 296, 8);                                  \
    B0 = swf8[(KB) * 64 + lane];        B1 = swf8[(12 + (KB)) * 64 + lane];   \
  } while (0)

#pragma unroll
  for (int tp = 0; tp < 2; ++tp) {
    const int tpadd = tp * 576;
    f32x16 a0 = {}, a1 = {}, a2 = {}, a3 = {};
    F f0a, f1a, f0b, f1b;
    half8 b0a, b1a, b0b, b1b;
    LOADF(f0a, f1a, b0a, b1a, 0, tpadd);
#pragma unroll
    for (int kb = 0; kb < 12; kb += 2) {
      LOADF(f0b, f1b, b0b, b1b, kb + 1, tpadd);
      a0 = __builtin_amdgcn_mfma_f32_32x32x16_f16(f0a.v, b0a, a0, 0, 0, 0);
      a1 = __builtin_amdgcn_mfma_f32_32x32x16_f16(f0a.v, b1a, a1, 0, 0, 0);
      a2 = __builtin_amdgcn_mfma_f32_32x32x16_f16(f1a.v, b0a, a2, 0, 0, 0);
      a3 = __builtin_amdgcn_mfma_f32_32x32x16_f16(f1a.v, b1a, a3, 0, 0, 0);
      if (kb + 2 < 12) LOADF(f0a, f1a, b0a, b1a, kb + 2, tpadd);
      a0 = __builtin_amdgcn_mfma_f32_32x32x16_f16(f0b.v, b0b, a0, 0, 0, 0);
      a1 = __builtin_amdgcn_mfma_f32_32x32x16_f16(f0b.v, b1b, a1, 0, 0, 0);
      a2 = __builtin_amdgcn_mfma_f32_32x32x16_f16(f1b.v, b0b, a2, 0, 0, 0);
      a3 = __builtin_amdgcn_mfma_f32_32x32x16_f16(f1b.v, b1b, a3, 0, 0, 0);
    }
    float s0 = 0.f, s1 = 0.f;
#pragma unroll
    for (int r = 0; r < 16; ++r) {
      s0 += fmaxf(a0[r] + bias0, 0.f) + fmaxf(a2[r] + bias0, 0.f);
      s1 += fmaxf(a1[r] + bias1, 0.f) + fmaxf(a3[r] + bias1, 0.f);
    }
    pool0 += s0;
    pool1 += s1;
  }
#undef LOADF

  pool0 += __shfl_xor(pool0, 32);
  pool1 += __shfl_xor(pool1, 32);
  if (lane < 32) {
    s_pool[w * 64 + lo] = pool0;
    s_pool[w * 64 + 32 + lo] = pool1;
  }
  __syncthreads();
  if (tid < 64) {
    float s = s_pool[tid] + s_pool[64 + tid] + s_pool[128 + tid] + s_pool[192 + tid];
    atomicAdd(&enc[n * 64 + tid], s * (1.f / 1024.f));   // 2 addends: order-invariant
  }
}

// ---------- proj: relu(enc @ pw + pb) -> h16 [2048][512] fp16 ----------
__global__ __launch_bounds__(256) void proj_kernel(
    const float* __restrict__ enc, const float* __restrict__ pw,
    const float* __restrict__ pb, ushort* __restrict__ h16) {
  int c = ((blockIdx.x & 1) << 8) | threadIdx.x;
  int r0 = (blockIdx.x >> 1) << 3;
  float bias = pb[c];
  float acc[8];
#pragma unroll
  for (int r = 0; r < 8; ++r) acc[r] = bias;
#pragma unroll 4
  for (int k = 0; k < 64; ++k) {
    float w = pw[k * 512 + c];
#pragma unroll
    for (int r = 0; r < 8; ++r) acc[r] = fmaf(enc[(r0 + r) * 64 + k], w, acc[r]);
  }
#pragma unroll
  for (int r = 0; r < 8; ++r)
    h16[(r0 + r) * 512 + c] = __builtin_bit_cast(ushort, (_Float16)fmaxf(acc[r], 0.f));
}

// ---------- GNN GEMM (r13 structure, split-K x2): part[split] = h@Ws + agg@Wn over K-half ----------
// grid 512: split = bid>>8, bm = (bid>>3)&31, bn = bid&7; 2 blocks/CU -> 8 waves/CU.
// Per block: 4 K-iterations (vs 8) of the identical STAGE/GATHER/COMBINE/MFMA loop.
__global__ __launch_bounds__(256) void gnn_gemm_kernel(
    const ushort* __restrict__ h16, const int* __restrict__ nbr,
    const float* __restrict__ den,
    const ushort* __restrict__ Ws, const ushort* __restrict__ Wn,
    float* __restrict__ part) {
  __shared__ ushort s_lds[2][16384];
  __shared__ int s_nbr[320];
  __shared__ float s_den[64];
  const int tid = threadIdx.x;
  const int lane = tid & 63;
  const int hi = lane >> 5, lo = lane & 31;
  const int wu = __builtin_amdgcn_readfirstlane(tid >> 6);
  const int wr = wu >> 1, wc = wu & 1;
  const int split = blockIdx.x >> 8;
  const int bm = (blockIdx.x >> 3) & 31, bn = blockIdx.x & 7;
  const int r0 = bm << 6, c0 = bn << 6;
  const int itb = split << 2;           // global 64-k step base for this split

  if (tid < 80) ((int4*)s_nbr)[tid] = ((const int4*)(nbr + r0 * 5))[tid];
  else if (tid < 96) ((float4*)s_den)[tid - 80] = ((const float4*)(den + r0))[tid - 80];
  __syncthreads();

  const int grow = tid >> 2, gseg = tid & 3;
  int gj[5];
  uint gm[5];
#pragma unroll
  for (int k = 0; k < 5; ++k) {
    int j = s_nbr[grow * 5 + k];
    gm[k] = (j >= 0) ? 0xFFFFFFFFu : 0u;
    gj[k] = (j >= 0) ? j : 0;
  }
  half8 den8;
  {
    _Float16 dh = (_Float16)s_den[grow];
#pragma unroll
    for (int e = 0; e < 8; ++e) den8[e] = dh;
  }

  union GU { half8 v; uint u[4]; };
  GU ga[5][2];

  auto GATHER = [&](int it) {
    const ushort* hb = h16 + (it << 6) + gseg * 16;
#pragma unroll
    for (int k = 0; k < 5; ++k) {
      const half8* p = (const half8*)(hb + gj[k] * 512);
      ga[k][0].v = p[0];
      ga[k][1].v = p[1];
    }
  };
  auto COMBINE = [&](int buf) {
#pragma unroll
    for (int part2 = 0; part2 < 2; ++part2) {
      GU t0, t1, t2, t3, t4;
#pragma unroll
      for (int j2 = 0; j2 < 4; ++j2) {
        t0.u[j2] = ga[0][part2].u[j2] & gm[0];
        t1.u[j2] = ga[1][part2].u[j2] & gm[1];
        t2.u[j2] = ga[2][part2].u[j2] & gm[2];
        t3.u[j2] = ga[3][part2].u[j2] & gm[3];
        t4.u[j2] = ga[4][part2].u[j2] & gm[4];
      }
      half8 s = ((t0.v + t1.v) + (t2.v + t3.v)) + t4.v;
      s = s * den8;
      *(half8*)&s_lds[buf][4096 + (2 * gseg + part2) * 512 + grow * 8] = s;
    }
  };
  auto STAGE = [&](int buf, int it) {
    int k0 = it << 6;
    const ushort* ph = h16 + (r0 + lane) * 512 + k0 + 8 * wu;
    const ushort* ps = Ws + (c0 + lane) * 512 + k0 + 8 * wu;
    const ushort* pn = Wn + (c0 + lane) * 512 + k0 + 8 * wu;
    ushort* lb = &s_lds[buf][wu << 9];
#define GLDS(SRC, DST) __builtin_amdgcn_global_load_lds( \
      (const __attribute__((address_space(1))) void*)(SRC), \
      (__attribute__((address_space(3))) void*)(DST), 16, 0, 0)
    GLDS(ph, lb);            GLDS(ph + 32, lb + 2048);
    GLDS(ps, lb + 8192);     GLDS(ps + 32, lb + 10240);
    GLDS(pn, lb + 12288);    GLDS(pn + 32, lb + 14336);
#undef GLDS
  };

  f32x16 accS = {}, accN = {};
  GATHER(itb);
  STAGE(0, itb);
  COMBINE(0);
  __syncthreads();
  int cur = 0;
  for (int it = 0; it < 4; ++it) {
    if (it < 3) {
      GATHER(itb + it + 1);
      STAGE(cur ^ 1, itb + it + 1);
    }
    const half8* pAh = (const half8*)&s_lds[cur][0];
    const half8* pAg = (const half8*)&s_lds[cur][4096];
    const half8* pBs = (const half8*)&s_lds[cur][8192];
    const half8* pBn = (const half8*)&s_lds[cur][12288];
#pragma unroll
    for (int ks = 0; ks < 4; ++ks) {
      int gi = (2 * ks + hi) * 64;
      half8 ah = pAh[gi + 32 * wr + lo];
      half8 bs = pBs[gi + 32 * wc + lo];
      accS = __builtin_amdgcn_mfma_f32_32x32x16_f16(ah, bs, accS, 0, 0, 0);
      half8 ag = pAg[gi + 32 * wr + lo];
      half8 bn2 = pBn[gi + 32 * wc + lo];
      accN = __builtin_amdgcn_mfma_f32_32x32x16_f16(ag, bn2, accN, 0, 0, 0);
    }
    if (it < 3) COMBINE(cur ^ 1);
    __syncthreads();
    cur ^= 1;
  }

  const int col = c0 + 32 * wc + lo;
  float* dst = part + (size_t)split * (NNODES * 512);
#pragma unroll
  for (int r = 0; r < 16; ++r) {
    int row = r0 + 32 * wr + (r & 3) + ((r >> 2) << 3) + (hi << 2);
    dst[row * 512 + col] = accS[r] + accN[r];
  }
}

// ---------- reduce: out = relu(part0 + part1 + bias) ----------
__global__ __launch_bounds__(256) void gnn_reduce_kernel(
    const float* __restrict__ part, const float* __restrict__ bg,
    ushort* __restrict__ hout, float* __restrict__ fout, int final_layer) {
  int i = blockIdx.x * 256 + threadIdx.x;   // float4 index, 262144 total
  float4 a = ((const float4*)part)[i];
  float4 b = ((const float4*)part)[i + 262144];
  float4 bb = ((const float4*)bg)[i & 127];
  float4 o;
  o.x = fmaxf(a.x + b.x + bb.x, 0.f);
  o.y = fmaxf(a.y + b.y + bb.y, 0.f);
  o.z = fmaxf(a.z + b.z + bb.z, 0.f);
  o.w = fmaxf(a.w + b.w + bb.w, 0.f);
  if (final_layer) {
    ((float4*)fout)[i] = o;
  } else {
    ushort4 h;
    h.x = __builtin_bit_cast(ushort, (_Float16)o.x);
    h.y = __builtin_bit_cast(ushort, (_Float16)o.y);
    h.z = __builtin_bit_cast(ushort, (_Float16)o.z);
    h.w = __builtin_bit_cast(ushort, (_Float16)o.w);
    ((ushort4*)hout)[i] = h;
  }
}

extern "C" void kernel_launch(void* const* d_in, const int* in_sizes, int n_in,
                              void* d_out, int out_size, void* d_ws, size_t ws_size,
                              hipStream_t stream) {
  const float* imgs   = (const float*)d_in[0];
  const float* pos    = (const float*)d_in[1];
  const float* conv_w = (const float*)d_in[2];
  const float* conv_b = (const float*)d_in[3];
  const float* proj_w = (const float*)d_in[4];
  const float* proj_b = (const float*)d_in[5];
  const float* w_self = (const float*)d_in[6];
  const float* w_nbr  = (const float*)d_in[7];
  const float* b_gnn  = (const float*)d_in[8];

  char* ws = (char*)d_ws;
  ushort* wfrag = (ushort*)(ws);
  float*  enc   = (float*) (ws + 32768);
  ushort* h16a  = (ushort*)(ws + 557056);
  ushort* h16b  = (ushort*)(ws + 2654208);
  ushort* wT16  = (ushort*)(ws + 6848512);
  int*    nbr   = (int*)   (ws + 11042816);
  float*  den   = (float*) (ws + 11083776);
  float*  part  = (float*) (ws + 11534336);

  setup_kernel<<<2608, 256, 0, stream>>>(conv_w, w_self, w_nbr, pos,
                                         wfrag, wT16, nbr, den, enc);
  conv_pool_kernel<<<2 * NNODES, 256, 0, stream>>>(imgs, wfrag, conv_b, enc);
  proj_kernel<<<512, 256, 0, stream>>>(enc, proj_w, proj_b, h16a);

  for (int l = 0; l < 4; ++l) {
    ushort* hin  = (l & 1) ? h16b : h16a;
    ushort* hnew = (l & 1) ? h16a : h16b;
    gnn_gemm_kernel<<<512, 256, 0, stream>>>(
        hin, nbr, den, wT16 + l * 262144, wT16 + (4 + l) * 262144, part);
    gnn_reduce_kernel<<<1024, 256, 0, stream>>>(
        part, b_gnn + l * 512, hnew, (float*)d_out, (l == 3) ? 1 : 0);
  }
}